// Round 4
// baseline (222.622 us; speedup 1.0000x reference)
//
#include <hip/hip_runtime.h>
#include <hip/hip_bf16.h>

// LSTM cell, B=4096, IN=1024, H=1024, K = IN+H = 2048. All I/O float32.
// Pass 1 convert_pack: X=concat(input,hx) -> bf16 Xb; W -> bf16 Wp (rows
//   permuted into the 256-wide-gate-tile staging order of pass 2).
// Pass 2 lstm_gemm8: 256x256 tile, BK=64, 512 thr / 8 waves (2x4), 32x32x16
//   MFMA, double-buffered LDS (128 KB), 8 phases per 2 K-tiles.
//   R4: REG-STAGED staging (global->VGPR->ds_write, T14 async split) replaces
//   global_load_lds. R1/R3 showed the compiler's LDS-DMA alias tracking
//   inserts per-phase drains before C++ ds_reads when DMA is in flight
//   (98us, MfmaUtil 29%, phase=1837cyc vs 512cyc MFMA floor). With pure
//   C++ loads/ds_writes/ds_reads every dependency is compiler-visible and
//   waits are counted, not drained. Phases restructured to 4 M-strips/tile
//   (a[4]=16 regs, B held 4 phases) to pay for the 16 staging VGPRs.
//   Load issued 2 phases before its ds_write; write 4+ phases before read;
//   all buffer turnover separated by >=1 barrier after reader lgkm-drain.

typedef __attribute__((ext_vector_type(8))) __bf16 bf16x8;
typedef __attribute__((ext_vector_type(16))) float f32x16;

__device__ __forceinline__ unsigned short f2bf(float f) {
  union { float f; unsigned int u; } v; v.f = f;
  unsigned int u = v.u + 0x7FFF + ((v.u >> 16) & 1);  // round-to-nearest-even
  return (unsigned short)(u >> 16);
}
__device__ __forceinline__ unsigned int pack2(float a, float b) {
  return (unsigned int)f2bf(a) | ((unsigned int)f2bf(b) << 16);
}

__device__ __forceinline__ float sigmoidf_fast(float x) {
  return 1.0f / (1.0f + __expf(-x));
}
__device__ __forceinline__ float tanhf_fast(float x) {
  return 1.0f - 2.0f / (__expf(2.0f * x) + 1.0f);
}

// ---------------- Pass 1: fp32 -> bf16 conversion + W permutation ----------
// Wp physical row q (within 256-row block nb): q = nb*256 + h*128 + wcp*32 + r32
// holds gate g = h*2 + (r32>>4), hidden = nb*64 + wcp*16 + (r32&15).
__global__ __launch_bounds__(256) void convert_pack(
    const float* __restrict__ xin, const float* __restrict__ hx,
    const float* __restrict__ Wi, const float* __restrict__ Wf,
    const float* __restrict__ Wg, const float* __restrict__ Wo,
    unsigned short* __restrict__ Xb, unsigned short* __restrict__ Wp) {
  const int t = blockIdx.x * 256 + threadIdx.x;
  const float* src;
  unsigned short* dst;
  if (t < (1 << 20)) {
    const int e = t * 8;
    const int row = e >> 11, k = e & 2047;
    src = (k < 1024) ? (xin + (size_t)row * 1024 + k)
                     : (hx + (size_t)row * 1024 + (k - 1024));
    dst = Xb + e;
  } else {
    const int e = (t - (1 << 20)) * 8;
    const int q = e >> 11, k = e & 2047;
    const int nb = q >> 8, rem = q & 255;
    const int h = rem >> 7, wcp = (rem >> 5) & 3, r32 = rem & 31;
    const int gate = h * 2 + (r32 >> 4);
    const int hidden = nb * 64 + wcp * 16 + (r32 & 15);
    const float* W = gate == 0 ? Wi : (gate == 1 ? Wf : (gate == 2 ? Wg : Wo));
    src = W + (size_t)hidden * 2048 + k;
    dst = Wp + e;
  }
  const float4 lo = *(const float4*)src;
  const float4 hi = *(const float4*)(src + 4);
  uint4 p;
  p.x = pack2(lo.x, lo.y);
  p.y = pack2(lo.z, lo.w);
  p.z = pack2(hi.x, hi.y);
  p.w = pack2(hi.z, hi.w);
  *(uint4*)dst = p;
}

// ---------------- Pass 2: 8-phase MFMA GEMM + fused LSTM gating ------------

#define BAR __builtin_amdgcn_s_barrier()
#define SP1 __builtin_amdgcn_s_setprio(1)
#define SP0 __builtin_amdgcn_s_setprio(0)

// ---- global loads into staging regs (16 B each, coalesced) ----
// A half H of tile T: rows H*64+{r8, 128+r8}
#define GLA(SG, H, T)                                                          \
  do {                                                                         \
    SG##0 = *(const uint4*)(aSrc + (size_t)((H)*64) * 2048 + (T)*64);          \
    SG##1 = *(const uint4*)(aSrc + (size_t)((H)*64 + 128) * 2048 + (T)*64);    \
  } while (0)
// B half H of tile T: rows H*128+{r, 64+r}
#define GLB(SG, H, T)                                                          \
  do {                                                                         \
    SG##0 = *(const uint4*)(bSrc + (size_t)((H)*128) * 2048 + (T)*64);         \
    SG##1 = *(const uint4*)(bSrc + (size_t)((H)*128 + 64) * 2048 + (T)*64);    \
  } while (0)
// ---- ds_writes of a staged half-tile (linear dest, 16 B/thread x2) ----
#define DWA(SG, BUF, H)                                                        \
  do {                                                                         \
    *(uint4*)(aDst + (BUF)*16384 + (H)*8192) = SG##0;                          \
    *(uint4*)(aDst + (BUF)*16384 + (H)*8192 + 4096) = SG##1;                   \
  } while (0)
#define DWB(SG, BUF, H)                                                        \
  do {                                                                         \
    *(uint4*)(bDst + (BUF)*16384 + (H)*8192) = SG##0;                          \
    *(uint4*)(bDst + (BUF)*16384 + (H)*8192 + 4096) = SG##1;                   \
  } while (0)

// read A strip M (rows wr*128 + M*32 + l31) of buffer BUF -> a[4]
#define RD_AS(BUF, M)                                                          \
  _Pragma("unroll") for (int kk = 0; kk < 4; ++kk)                             \
      a[kk] = *(const bf16x8*)(Asb + (BUF)*16384 + ((M) >> 1) * 8192 + arow2 + \
                               (((M)&1) * 2048) + (((kk * 2 + ghi) ^ sxor) << 3));
// read B half N of buffer BUF into BR[]  (4 x ds_read_b128)
#define RD_B(BUF, N, BR)                                                       \
  _Pragma("unroll") for (int kk = 0; kk < 4; ++kk)                             \
      BR[kk] = *(const bf16x8*)(Bsb + (BUF)*16384 + (N)*8192 + brow +          \
                                (((kk * 2 + ghi) ^ sxor) << 3));
// 8 MFMAs: M-strip M x both N-halves x full K=64
#define MMP(M)                                                                 \
  _Pragma("unroll") for (int kk = 0; kk < 4; ++kk) {                           \
    acc[M][0] = __builtin_amdgcn_mfma_f32_32x32x16_bf16(a[kk], b0[kk],         \
                                                        acc[M][0], 0, 0, 0);   \
    acc[M][1] = __builtin_amdgcn_mfma_f32_32x32x16_bf16(a[kk], b1[kk],         \
                                                        acc[M][1], 0, 0, 0);   \
  }

__global__ __launch_bounds__(512, 2) void lstm_gemm8(
    const unsigned short* __restrict__ Xb, const unsigned short* __restrict__ Wp,
    const float* __restrict__ cx,
    const float* __restrict__ bi, const float* __restrict__ bfv,
    const float* __restrict__ bg, const float* __restrict__ bo,
    float* __restrict__ out) {
  // A: [buf][h][p][r][k]  (h = 64-row half; p = wr; r in [0,64); k in [0,64))
  // B: [buf][h][wcp][r32][k]  (h = n half; wcp = wc; r32 in [0,32))
  __shared__ unsigned short As[2][2][2][64][64];  // 64 KB
  __shared__ unsigned short Bs[2][2][4][32][64];  // 64 KB

  const int tid = threadIdx.x;
  const int lane = tid & 63;
  const int wid = tid >> 6;          // 0..7
  const int wr = wid >> 2;           // 0..1  (128-row half)
  const int wc = wid & 3;            // 0..3  (64-col slice)
  const int l31 = lane & 31;
  const int ghi = lane >> 5;         // k-half within fragment
  const int sxor = l31 & 7;

  const int mbase = blockIdx.x * 256;  // batch tile
  const int nb = blockIdx.y;           // 64-hidden-col block

  // ---- staging sources (slot s_phys=tid&7 holds logical slot s^((row)&7)) --
  const int r8 = tid >> 3;                       // 0..63
  const int jsw = (tid & 7) ^ (r8 & 7);
  const unsigned short* aSrc = Xb + (size_t)(mbase + r8) * 2048 + jsw * 8;
  const unsigned short* bSrc =
      Wp + (size_t)(nb * 256 + (tid >> 8) * 32 + (r8 & 31)) * 2048 + jsw * 8;
  unsigned short* aDst = &As[0][0][0][0][0] + tid * 8;
  unsigned short* bDst = &Bs[0][0][0][0][0] + tid * 8;

  const unsigned short* Asb = &As[0][0][0][0][0];
  const unsigned short* Bsb = &Bs[0][0][0][0][0];
  const int arow2 = wr * 4096 + l31 * 64;
  const int brow = wc * 2048 + l31 * 64;

  f32x16 acc[4][2] = {};   // [m-strip 0..3][n-half 0..1], 128 acc regs
  bf16x8 a[4], b0[4], b1[4];
  uint4 s00, s01, s10, s11;  // two in-flight staging sets (16 VGPRs)

  // ---- prologue: tile0 fully staged; tile1 A-halves loaded (written ph0/1) --
  GLA(s0, 0, 0); GLA(s1, 1, 0); DWA(s0, 0, 0); DWA(s1, 0, 1);
  GLB(s0, 0, 0); GLB(s1, 1, 0); DWB(s0, 0, 0); DWB(s1, 0, 1);
  GLA(s0, 0, 1); GLA(s1, 1, 1);
  asm volatile("s_waitcnt lgkmcnt(0)" ::: "memory");  // one-time drain
  BAR;

  // ---- main loop: 15 iters x 2 K-tiles (tiles 0..29); tiles 30/31 peeled ---
  int kt = 0;
  for (int i = 0; i < 15; ++i, kt += 2) {
    // ph0: compute T(kt) buf0 strip0; write T+1 A-h0; load B-h0(T+1)
    DWA(s0, 1, 0);
    RD_AS(0, 0); RD_B(0, 0, b0); RD_B(0, 1, b1);
    GLB(s0, 0, kt + 1);
    BAR; SP1; MMP(0); SP0; BAR;
    // ph1: strip1; write T+1 A-h1; load B-h1(T+1)
    DWA(s1, 1, 1);
    RD_AS(0, 1);
    GLB(s1, 1, kt + 1);
    BAR; SP1; MMP(1); SP0; BAR;
    // ph2: strip2; write T+1 B-h0; load A-h0(T+2)
    DWB(s0, 1, 0);
    RD_AS(0, 2);
    GLA(s0, 0, kt + 2);
    BAR; SP1; MMP(2); SP0; BAR;
    // ph3: strip3; write T+1 B-h1; load A-h1(T+2)
    DWB(s1, 1, 1);
    RD_AS(0, 3);
    GLA(s1, 1, kt + 2);
    BAR; SP1; MMP(3); SP0; BAR;
    // ph4: compute T(kt+1) buf1 strip0; write T+2 A-h0; load B-h0(T+2)
    DWA(s0, 0, 0);
    RD_AS(1, 0); RD_B(1, 0, b0); RD_B(1, 1, b1);
    GLB(s0, 0, kt + 2);
    BAR; SP1; MMP(0); SP0; BAR;
    // ph5: strip1; write T+2 A-h1; load B-h1(T+2)
    DWA(s1, 0, 1);
    RD_AS(1, 1);
    GLB(s1, 1, kt + 2);
    BAR; SP1; MMP(1); SP0; BAR;
    // ph6: strip2; write T+2 B-h0; load A-h0(T+3)
    DWB(s0, 0, 0);
    RD_AS(1, 2);
    GLA(s0, 0, kt + 3);
    BAR; SP1; MMP(2); SP0; BAR;
    // ph7: strip3; write T+2 B-h1; load A-h1(T+3)
    DWB(s1, 0, 1);
    RD_AS(1, 3);
    GLA(s1, 1, kt + 3);
    BAR; SP1; MMP(3); SP0; BAR;
  }
  // ---- peel: tiles 30 (buf0) / 31 (buf1); finish staging tile 31 ----------
  DWA(s0, 1, 0);
  RD_AS(0, 0); RD_B(0, 0, b0); RD_B(0, 1, b1);
  GLB(s0, 0, 31);
  BAR; SP1; MMP(0); SP0; BAR;
  DWA(s1, 1, 1);
  RD_AS(0, 1);
  GLB(s1, 1, 31);
  BAR; SP1; MMP(1); SP0; BAR;
  DWB(s0, 1, 0);
  RD_AS(0, 2);
  BAR; SP1; MMP(2); SP0; BAR;
  DWB(s1, 1, 1);
  RD_AS(0, 3);
  BAR; SP1; MMP(3); SP0; BAR;
  RD_AS(1, 0); RD_B(1, 0, b0); RD_B(1, 1, b1);
  BAR; SP1; MMP(0); SP0; BAR;
  RD_AS(1, 1);
  BAR; SP1; MMP(1); SP0; BAR;
  RD_AS(1, 2);
  BAR; SP1; MMP(2); SP0; BAR;
  RD_AS(1, 3);
  BAR; SP1; MMP(3); SP0;

  // ---- fused LSTM epilogue (proven 32x32 C-layout + shfl_xor(16)) ----------
  // col c = wc*64 + n*32 + l31 -> gate = n*2 + (l31>>4), hidden = nb*64+wc*16+l15
  const int p = (l31 >> 4) & 1;  // 0: lane holds (i,g); 1: (f,o)
  const int nh = nb * 64 + wc * 16 + (l31 & 15);
  const float bias0 = p ? bfv[nh] : bi[nh];
  const float bias1 = p ? bo[nh] : bg[nh];

  float* outh = out;
  float* outc = out + (size_t)4096 * 1024;

#pragma unroll
  for (int m = 0; m < 4; ++m) {
#pragma unroll
    for (int r = 0; r < 16; ++r) {
      const int row = mbase + wr * 128 + m * 32 + (r & 3) + 8 * (r >> 2) + 4 * ghi;
      const size_t idx = (size_t)row * 1024 + nh;
      const float own0 = acc[m][0][r] + bias0;
      const float own1 = acc[m][1][r] + bias1;
      const float rcv0 = __shfl_xor(own0, 16);
      const float rcv1 = __shfl_xor(own1, 16);
      const float zi = p ? rcv0 : own0;
      const float zf = p ? own0 : rcv0;
      const float zg = p ? rcv1 : own1;
      const float zo = p ? own1 : rcv1;
      const float it = sigmoidf_fast(zi);
      const float ft = sigmoidf_fast(zf);
      const float gt = tanhf_fast(zg);
      const float ot = sigmoidf_fast(zo);
      const float cv = ft * cx[idx] + it * gt;
      const float hv = ot * tanhf_fast(cv);
      float* dst = p ? (outc + idx) : (outh + idx);
      *dst = p ? cv : hv;
    }
  }
}

// ---------------- Fallback (R2): single fused kernel, no workspace ----------
__global__ __launch_bounds__(256) void lstm_fused_fb(
    const float* __restrict__ xin, const float* __restrict__ hx,
    const float* __restrict__ cx,
    const float* __restrict__ Wi, const float* __restrict__ bi,
    const float* __restrict__ Wf, const float* __restrict__ bfv,
    const float* __restrict__ Wg, const float* __restrict__ bg,
    const float* __restrict__ Wo, const float* __restrict__ bo,
    float* __restrict__ out) {
  typedef __attribute__((ext_vector_type(4))) float f32x4;
  __shared__ unsigned short As[128 * 32];
  __shared__ unsigned short Bs[128 * 32];

  const int tid = threadIdx.x;
  const int lane = tid & 63;
  const int wid = tid >> 6;
  const int wr = wid >> 1, wc = wid & 1;
  const int lane15 = lane & 15, quad = lane >> 4;
  const int mbase = blockIdx.x * 128;
  const int nbase = blockIdx.y * 32;

  const int kofs = (tid & 3) * 8;
  const size_t a_off0 = (size_t)(mbase + (tid >> 2)) * 1024 + kofs;
  const size_t a_off1 = a_off0 + (size_t)64 * 1024;

  auto wsel = [&](int g) { return g == 0 ? Wi : (g == 1 ? Wf : (g == 2 ? Wg : Wo)); };
  const int rb0 = tid >> 2;
  const int rb1 = rb0 + 64;
  const float* bsrc0 =
      wsel((rb0 >> 4) & 3) + (size_t)(nbase + (rb0 >> 6) * 16 + (rb0 & 15)) * 2048 + kofs;
  const float* bsrc1 =
      wsel((rb1 >> 4) & 3) + (size_t)(nbase + (rb1 >> 6) * 16 + (rb1 & 15)) * 2048 + kofs;

  uint4* lA0 = (uint4*)(As + (size_t)tid * 8);
  uint4* lA1 = (uint4*)(As + (size_t)(tid + 256) * 8);
  uint4* lB0 = (uint4*)(Bs + (size_t)tid * 8);
  uint4* lB1 = (uint4*)(Bs + (size_t)(tid + 256) * 8);

  f32x4 acc[4][4] = {};

  for (int kt = 0; kt < 64; ++kt) {
    const int kc = kt * 32;
    const float* abase = (kc < 1024 ? xin : hx) + (kc & 1023);
    const float4 a0lo = *(const float4*)(abase + a_off0);
    const float4 a0hi = *(const float4*)(abase + a_off0 + 4);
    const float4 a1lo = *(const float4*)(abase + a_off1);
    const float4 a1hi = *(const float4*)(abase + a_off1 + 4);
    const float4 b0lo = *(const float4*)(bsrc0 + kc);
    const float4 b0hi = *(const float4*)(bsrc0 + kc + 4);
    const float4 b1lo = *(const float4*)(bsrc1 + kc);
    const float4 b1hi = *(const float4*)(bsrc1 + kc + 4);

    uint4 pa0, pa1, pb0, pb1;
    pa0.x = pack2(a0lo.x, a0lo.y); pa0.y = pack2(a0lo.z, a0lo.w);
    pa0.z = pack2(a0hi.x, a0hi.y); pa0.w = pack2(a0hi.z, a0hi.w);
    pa1.x = pack2(a1lo.x, a1lo.y); pa1.y = pack2(a1lo.z, a1lo.w);
    pa1.z = pack2(a1hi.x, a1hi.y); pa1.w = pack2(a1hi.z, a1hi.w);
    pb0.x = pack2(b0lo.x, b0lo.y); pb0.y = pack2(b0lo.z, b0lo.w);
    pb0.z = pack2(b0hi.x, b0hi.y); pb0.w = pack2(b0hi.z, b0hi.w);
    pb1.x = pack2(b1lo.x, b1lo.y); pb1.y = pack2(b1lo.z, b1lo.w);
    pb1.z = pack2(b1hi.x, b1hi.y); pb1.w = pack2(b1hi.z, b1hi.w);

    __syncthreads();
    *lA0 = pa0; *lA1 = pa1; *lB0 = pb0; *lB1 = pb1;
    __syncthreads();

    bf16x8 aa[4], bb[4];
#pragma unroll
    for (int i = 0; i < 4; ++i)
      aa[i] = *reinterpret_cast<const bf16x8*>(&As[(wr * 64 + i * 16 + lane15) * 32 + quad * 8]);
#pragma unroll
    for (int j = 0; j < 4; ++j)
      bb[j] = *reinterpret_cast<const bf16x8*>(&Bs[(wc * 64 + j * 16 + lane15) * 32 + quad * 8]);
#pragma unroll
    for (int i = 0; i < 4; ++i)
#pragma unroll
      for (int j = 0; j < 4; ++j)
        acc[i][j] = __builtin_amdgcn_mfma_f32_16x16x32_bf16(aa[i], bb[j], acc[i][j], 0, 0, 0);
  }

  const int n = nbase + wc * 16 + lane15;
  const float bias_i = bi[n];
  const float bias_f = bfv[n];
  const float bias_g = bg[n];
  const float bias_o = bo[n];
  float* outh = out;
  float* outc = out + (size_t)4096 * 1024;

#pragma unroll
  for (int i = 0; i < 4; ++i) {
#pragma unroll
    for (int r = 0; r < 4; ++r) {
      const int mb = mbase + wr * 64 + i * 16 + quad * 4 + r;
      const size_t idx = (size_t)mb * 1024 + n;
      const float it = sigmoidf_fast(acc[i][0][r] + bias_i);
      const float ft = sigmoidf_fast(acc[i][1][r] + bias_f);
      const float gt = tanhf_fast(acc[i][2][r] + bias_g);
      const float ot = sigmoidf_fast(acc[i][3][r] + bias_o);
      const float cv = ft * cx[idx] + it * gt;
      const float hv = ot * tanhf_fast(cv);
      outh[idx] = hv;
      outc[idx] = cv;
    }
  }
}

extern "C" void kernel_launch(void* const* d_in, const int* in_sizes, int n_in,
                              void* d_out, int out_size, void* d_ws, size_t ws_size,
                              hipStream_t stream) {
  const float* xin = (const float*)d_in[0];
  const float* hx  = (const float*)d_in[1];
  const float* cx  = (const float*)d_in[2];
  const float* Wi  = (const float*)d_in[3];
  const float* bi  = (const float*)d_in[4];
  const float* Wf  = (const float*)d_in[5];
  const float* bf  = (const float*)d_in[6];
  const float* Wg  = (const float*)d_in[7];
  const float* bg  = (const float*)d_in[8];
  const float* Wo  = (const float*)d_in[9];
  const float* bo  = (const float*)d_in[10];
  float* out = (float*)d_out;

  const size_t need = (size_t)2 * 4096 * 2048 * sizeof(unsigned short);  // 32 MB
  if (ws_size >= need) {
    unsigned short* Xb = (unsigned short*)d_ws;
    unsigned short* Wp = Xb + (size_t)4096 * 2048;
    convert_pack<<<8192, 256, 0, stream>>>(xin, hx, Wi, Wf, Wg, Wo, Xb, Wp);
    dim3 grid(4096 / 256, 1024 / 64);
    lstm_gemm8<<<grid, 512, 0, stream>>>(Xb, Wp, cx, bi, bf, bg, bo, out);
  } else {
    dim3 grid(4096 / 128, 1024 / 32);
    lstm_fused_fb<<<grid, 256, 0, stream>>>(xin, hx, cx, Wi, bi, Wf, bf, Wg, bg, Wo, bo, out);
  }
}